// Round 11
// baseline (126.080 us; speedup 1.0000x reference)
//
#include <hip/hip_runtime.h>
#include <hip/hip_bf16.h>

// Harness facts: inputs f32, output f32, threshold 2.5e-2 (bf16 cmp).
// ~85us of dur_us is harness 0xAA poison fills (2x268MB) -- fixed floor.
// r9/r10 attribution: 128-thr gemm = +9us (latency cliff); bf16-C pairwise
// = +4us (unpack VALU > LDS savings; pairwise is VALU-limited).
// This round: pairwise = exact r8 (f32 C); gemm = 64x64 tile, 4 waves of
// 32x32 wave-tiles (reads:MFMA 1.0, still 4-wave blocks), grid (8,16,3).
//   1. prep (2049 blocks): emb f32->bf16 | W_s1^T, W_e1^T -> bf16 | out[0:1024]=b_s2
//   2. gemm (8,16,3) x 256 thr: z=0 start-logits (atomicAdd out[0:1024]),
//      z=1 A_mat f32, z=2 C_mat = c + b_e1 (f32)
//   3. pairwise (8,16,2) x 512 thr: 32i x 64j, 2x2 micro, packed f32x2 math.

typedef float f32x4 __attribute__((ext_vector_type(4)));
typedef float f32x2 __attribute__((ext_vector_type(2)));
typedef __bf16 bf16x8 __attribute__((ext_vector_type(8)));

static __device__ __forceinline__ unsigned short f2bf(float f) {
  unsigned int u = __builtin_bit_cast(unsigned int, f);
  u += 0x7FFFu + ((u >> 16) & 1u);  // RNE
  return (unsigned short)(u >> 16);
}

// ----------------------------------------------------------------- prep
__global__ __launch_bounds__(256) void prep(
    const float* __restrict__ emb, const float* __restrict__ W_s1,
    const float* __restrict__ W_e1, const float* __restrict__ b_s2,
    unsigned short* __restrict__ emb_bf, unsigned short* __restrict__ Wt_s,
    unsigned short* __restrict__ Wt_e, float* __restrict__ out) {
  __shared__ float tile[32][33];
  int bx = blockIdx.x, t = threadIdx.x;
  if (bx < 512) {
    int i = bx * 2048 + t * 8;
    f32x4 v0 = *(const f32x4*)&emb[i];
    f32x4 v1 = *(const f32x4*)&emb[i + 4];
    ushort4 o0, o1;
    o0.x = f2bf(v0[0]); o0.y = f2bf(v0[1]);
    o0.z = f2bf(v0[2]); o0.w = f2bf(v0[3]);
    o1.x = f2bf(v1[0]); o1.y = f2bf(v1[1]);
    o1.z = f2bf(v1[2]); o1.w = f2bf(v1[3]);
    *(ushort4*)&emb_bf[i] = o0;
    *(ushort4*)&emb_bf[i + 4] = o1;
  } else if (bx < 2048) {
    const float* in;
    unsigned short* o;
    int R, tid;
    if (bx < 1024) { tid = bx - 512;  in = W_s1; o = Wt_s; R = 1024; }
    else           { tid = bx - 1024; in = W_e1; o = Wt_e; R = 2048; }
    int r0 = (tid >> 4) * 32, c0 = (tid & 15) * 32;
    int a = t >> 3, b4 = t & 7;
    f32x4 v = *(const f32x4*)&in[(size_t)(r0 + a) * 512 + c0 + b4 * 4];
    tile[a][b4 * 4 + 0] = v[0];
    tile[a][b4 * 4 + 1] = v[1];
    tile[a][b4 * 4 + 2] = v[2];
    tile[a][b4 * 4 + 3] = v[3];
    __syncthreads();
    ushort4 o4;
    o4.x = f2bf(tile[b4 * 4 + 0][a]);
    o4.y = f2bf(tile[b4 * 4 + 1][a]);
    o4.z = f2bf(tile[b4 * 4 + 2][a]);
    o4.w = f2bf(tile[b4 * 4 + 3][a]);
    *(ushort4*)&o[(size_t)(c0 + a) * R + r0 + b4 * 4] = o4;
  } else {
    float v = b_s2[0];
    f32x4 o = {v, v, v, v};
    *(f32x4*)&out[t * 4] = o;
  }
}

// ----------------------------------------------------------------- GEMM
// M=1024, K=1024, N=512 per z. 256 thr = 4 waves; tile 64m x 64n; wave-tile
// 32x32 (2 af + 2 bf ds_reads -> 4 MFMA, ratio 1.0). K-step 64.
// Grid (8,16,3) = 384 blocks (1-2 blocks/CU, 4-8 waves/CU).
__global__ __launch_bounds__(256) void gemm_fused(
    const unsigned short* __restrict__ Aemb,   // [1024][1024] bf16
    const unsigned short* __restrict__ Wt_s,   // [512][1024] bf16
    const unsigned short* __restrict__ Wt_e,   // [512][2048] bf16
    const float* __restrict__ b_s1, const float* __restrict__ w_s2,
    const float* __restrict__ b_e1, float* __restrict__ out,
    float* __restrict__ A_mat, float* __restrict__ C_mat) {
  __shared__ unsigned short Al[64][72];
  __shared__ unsigned short Bl[64][72];
  int z = blockIdx.z;
  int n0 = blockIdx.x * 64;
  int m0 = blockIdx.y * 64;
  const unsigned short* Bmat = (z == 0) ? Wt_s : Wt_e;
  int bstride = (z == 0) ? 1024 : 2048;
  int bofs = (z == 2) ? 1024 : 0;

  int t = threadIdx.x, lane = t & 63, wave = t >> 6;
  int wm = (wave >> 1) * 32, wn = (wave & 1) * 32;
  int lm = lane & 15, g = lane >> 4;

  f32x4 acc[2][2];
#pragma unroll
  for (int mi = 0; mi < 2; ++mi)
#pragma unroll
    for (int ni = 0; ni < 2; ++ni) acc[mi][ni] = (f32x4){0.f, 0.f, 0.f, 0.f};

  int sr = t >> 2, sc = (t & 3) * 16;
  for (int k0 = 0; k0 < 1024; k0 += 64) {
    __syncthreads();
    const unsigned short* ap = &Aemb[(size_t)(m0 + sr) * 1024 + k0 + sc];
    *(uint4*)&Al[sr][sc] = *(const uint4*)ap;
    *(uint4*)&Al[sr][sc + 8] = *(const uint4*)(ap + 8);
    const unsigned short* bp =
        &Bmat[(size_t)(n0 + sr) * bstride + bofs + k0 + sc];
    *(uint4*)&Bl[sr][sc] = *(const uint4*)bp;
    *(uint4*)&Bl[sr][sc + 8] = *(const uint4*)(bp + 8);
    __syncthreads();
#pragma unroll
    for (int kk = 0; kk < 2; ++kk) {
      bf16x8 af[2], bf[2];
#pragma unroll
      for (int mi = 0; mi < 2; ++mi)
        af[mi] = *(const bf16x8*)&Al[wm + mi * 16 + lm][kk * 32 + g * 8];
#pragma unroll
      for (int ni = 0; ni < 2; ++ni)
        bf[ni] = *(const bf16x8*)&Bl[wn + ni * 16 + lm][kk * 32 + g * 8];
#pragma unroll
      for (int mi = 0; mi < 2; ++mi)
#pragma unroll
        for (int ni = 0; ni < 2; ++ni)
          acc[mi][ni] = __builtin_amdgcn_mfma_f32_16x16x32_bf16(
              af[mi], bf[ni], acc[mi][ni], 0, 0, 0);
    }
  }

  int col0 = n0 + wn + lm, col1 = n0 + wn + 16 + lm;
  if (z == 0) {
    float bs0 = b_s1[col0], bs1 = b_s1[col1];
    float ws0 = w_s2[col0], ws1 = w_s2[col1];
#pragma unroll
    for (int mi = 0; mi < 2; ++mi)
#pragma unroll
      for (int r = 0; r < 4; ++r) {
        float s = fmaxf(acc[mi][0][r] + bs0, 0.f) * ws0 +
                  fmaxf(acc[mi][1][r] + bs1, 0.f) * ws1;
        s += __shfl_xor(s, 1);
        s += __shfl_xor(s, 2);
        s += __shfl_xor(s, 4);
        s += __shfl_xor(s, 8);
        if (lm == 0) atomicAdd(&out[m0 + wm + mi * 16 + g * 4 + r], s);
      }
  } else if (z == 1) {
#pragma unroll
    for (int mi = 0; mi < 2; ++mi)
#pragma unroll
      for (int r = 0; r < 4; ++r) {
        int row = m0 + wm + mi * 16 + g * 4 + r;
        A_mat[(size_t)row * 512 + col0] = acc[mi][0][r];
        A_mat[(size_t)row * 512 + col1] = acc[mi][1][r];
      }
  } else {
    float b0 = b_e1[col0], b1 = b_e1[col1];
#pragma unroll
    for (int mi = 0; mi < 2; ++mi)
#pragma unroll
      for (int r = 0; r < 4; ++r) {
        int row = m0 + wm + mi * 16 + g * 4 + r;
        C_mat[(size_t)row * 512 + col0] = acc[mi][0][r] + b0;
        C_mat[(size_t)row * 512 + col1] = acc[mi][1][r] + b1;
      }
  }
}

// ------------------------------------------------------------- pairwise
// (r8 version) end[b,i,j] = sum_d relu(A[i,d]+C[j,d])*w[d] + b_e2.
// 512 thr, grid (8,16,2): 32i x 64j tile, 2x2 micro, d-pairs packed f32x2.
__global__ __launch_bounds__(512) void pairwise(
    const float* __restrict__ A_mat, const float* __restrict__ C_mat,
    const float* __restrict__ w_e2, const float* __restrict__ b_e2,
    float* __restrict__ out) {
  __shared__ f32x2 As_p[32][32];   // [dp][i]   8 KB (per 64-d chunk)
  __shared__ f32x2 Cs_p[32][64];   // [dp][j]  16 KB
  __shared__ f32x2 wl2[256];
  int t = threadIdx.x;
  int b = blockIdx.z;
  int j0 = blockIdx.x * 64, i0 = blockIdx.y * 32;

  if (t < 256) wl2[t] = *(const f32x2*)&w_e2[2 * t];
  float be2 = b_e2[0];

  int ti = t >> 5, tj = t & 31;
  f32x2 acc2[2][2];
#pragma unroll
  for (int q = 0; q < 2; ++q)
#pragma unroll
    for (int r = 0; r < 2; ++r) acc2[q][r] = (f32x2){0.f, 0.f};

  const float* Ab = A_mat + (size_t)(b * 512 + i0) * 512;
  const float* Cb = C_mat + (size_t)(b * 512 + j0) * 512;
  int si = t & 31, sq = t >> 5;  // A stage: row si, d-quad sq (0..15)
  int sj = t & 63, s2 = t >> 6;  // C stage: row sj, d-oct  s2 (0..7)
  f32x2 z2 = {0.f, 0.f};

  for (int ch = 0; ch < 8; ++ch) {
    __syncthreads();
    {
      f32x4 va = *(const f32x4*)&Ab[(size_t)si * 512 + ch * 64 + sq * 4];
      As_p[sq * 2 + 0][si] = (f32x2){va[0], va[1]};
      As_p[sq * 2 + 1][si] = (f32x2){va[2], va[3]};
      f32x4 v0 = *(const f32x4*)&Cb[(size_t)sj * 512 + ch * 64 + s2 * 8];
      f32x4 v1 = *(const f32x4*)&Cb[(size_t)sj * 512 + ch * 64 + s2 * 8 + 4];
      Cs_p[s2 * 4 + 0][sj] = (f32x2){v0[0], v0[1]};
      Cs_p[s2 * 4 + 1][sj] = (f32x2){v0[2], v0[3]};
      Cs_p[s2 * 4 + 2][sj] = (f32x2){v1[0], v1[1]};
      Cs_p[s2 * 4 + 3][sj] = (f32x2){v1[2], v1[3]};
    }
    __syncthreads();
#pragma unroll 8
    for (int dp = 0; dp < 32; ++dp) {
      f32x2 w2 = wl2[ch * 32 + dp];
      f32x4 av = *(const f32x4*)&As_p[dp][ti * 2];
      f32x4 cv = *(const f32x4*)&Cs_p[dp][tj * 2];
      f32x2 a0 = {av[0], av[1]}, a1 = {av[2], av[3]};
      f32x2 c0 = {cv[0], cv[1]}, c1 = {cv[2], cv[3]};
      acc2[0][0] += __builtin_elementwise_max(a0 + c0, z2) * w2;
      acc2[0][1] += __builtin_elementwise_max(a0 + c1, z2) * w2;
      acc2[1][0] += __builtin_elementwise_max(a1 + c0, z2) * w2;
      acc2[1][1] += __builtin_elementwise_max(a1 + c1, z2) * w2;
    }
  }

  float* oe = out + 1024;
#pragma unroll
  for (int q = 0; q < 2; ++q) {
    int i = i0 + ti * 2 + q;
    float2 vv;
    vv.x = acc2[q][0][0] + acc2[q][0][1] + be2;
    vv.y = acc2[q][1][0] + acc2[q][1][1] + be2;
    *(float2*)&oe[(size_t)(b * 512 + i) * 512 + j0 + tj * 2] = vv;
  }
}

// -------------------------------------------------------------------- launch
extern "C" void kernel_launch(void* const* d_in, const int* in_sizes, int n_in,
                              void* d_out, int out_size, void* d_ws,
                              size_t ws_size, hipStream_t stream) {
  const float* emb  = (const float*)d_in[0];
  const float* W_s1 = (const float*)d_in[1];
  const float* b_s1 = (const float*)d_in[2];
  const float* w_s2 = (const float*)d_in[3];
  const float* b_s2 = (const float*)d_in[4];
  const float* W_e1 = (const float*)d_in[5];
  const float* b_e1 = (const float*)d_in[6];
  const float* w_e2 = (const float*)d_in[7];
  const float* b_e2 = (const float*)d_in[8];
  float* out = (float*)d_out;

  char* ws = (char*)d_ws;
  unsigned short* emb_bf = (unsigned short*)(ws);                  // 2 MB
  unsigned short* Wt_s = (unsigned short*)(ws + 2u * (1u << 20));  // 1 MB
  unsigned short* Wt_e = (unsigned short*)(ws + 3u * (1u << 20));  // 2 MB
  float* A_mat = (float*)(ws + 5u * (1u << 20));                   // 2 MB
  float* C_mat = (float*)(ws + 7u * (1u << 20));                   // 2 MB

  hipLaunchKernelGGL(prep, dim3(2049), dim3(256), 0, stream,
                     emb, W_s1, W_e1, b_s2, emb_bf, Wt_s, Wt_e, out);
  hipLaunchKernelGGL(gemm_fused, dim3(8, 16, 3), dim3(256), 0, stream,
                     emb_bf, Wt_s, Wt_e, b_s1, w_s2, b_e1, out, A_mat, C_mat);
  hipLaunchKernelGGL(pairwise, dim3(8, 16, 2), dim3(512), 0, stream,
                     A_mat, C_mat, w_e2, b_e2, out);
}

// Round 13
// 121.274 us; speedup vs baseline: 1.0396x; 1.0396x over previous
//
#include <hip/hip_runtime.h>
#include <hip/hip_bf16.h>

// Harness facts: inputs f32, output f32, threshold 2.5e-2 (bf16 cmp).
// ~85us of dur_us is harness 0xAA poison fills (2x256MiB) -- fixed floor.
// r8-r11 scorecard: r8 config (gemm 64x32/768blk/4wave + f32 pairwise) = 118.6
// is the verified best; all ratio-improving gemm variants lost to occupancy/
// balance (r9 2-wave: +9; r11 384-blk: +7.5); bf16 pairwise: +4 (VALU-bound).
// This round: EXACT r8 + one delta: pairwise d-chunks 64->128 (halves
// barrier count 16->8; LDS 50KB still 1 block/CU).
//   1. prep (2049 blocks): emb f32->bf16 | W_s1^T, W_e1^T -> bf16 | out[0:1024]=b_s2
//   2. gemm (16,16,3) x 256 thr: 64m x 32n, wave-tile 16x32, 3 blocks/CU
//   3. pairwise (8,16,2) x 512 thr: 32i x 64j, 2x2 micro, packed f32x2,
//      128-d chunks.

typedef float f32x4 __attribute__((ext_vector_type(4)));
typedef float f32x2 __attribute__((ext_vector_type(2)));
typedef __bf16 bf16x8 __attribute__((ext_vector_type(8)));

static __device__ __forceinline__ unsigned short f2bf(float f) {
  unsigned int u = __builtin_bit_cast(unsigned int, f);
  u += 0x7FFFu + ((u >> 16) & 1u);  // RNE
  return (unsigned short)(u >> 16);
}

// ----------------------------------------------------------------- prep
__global__ __launch_bounds__(256) void prep(
    const float* __restrict__ emb, const float* __restrict__ W_s1,
    const float* __restrict__ W_e1, const float* __restrict__ b_s2,
    unsigned short* __restrict__ emb_bf, unsigned short* __restrict__ Wt_s,
    unsigned short* __restrict__ Wt_e, float* __restrict__ out) {
  __shared__ float tile[32][33];
  int bx = blockIdx.x, t = threadIdx.x;
  if (bx < 512) {
    int i = bx * 2048 + t * 8;
    f32x4 v0 = *(const f32x4*)&emb[i];
    f32x4 v1 = *(const f32x4*)&emb[i + 4];
    ushort4 o0, o1;
    o0.x = f2bf(v0[0]); o0.y = f2bf(v0[1]);
    o0.z = f2bf(v0[2]); o0.w = f2bf(v0[3]);
    o1.x = f2bf(v1[0]); o1.y = f2bf(v1[1]);
    o1.z = f2bf(v1[2]); o1.w = f2bf(v1[3]);
    *(ushort4*)&emb_bf[i] = o0;
    *(ushort4*)&emb_bf[i + 4] = o1;
  } else if (bx < 2048) {
    const float* in;
    unsigned short* o;
    int R, tid;
    if (bx < 1024) { tid = bx - 512;  in = W_s1; o = Wt_s; R = 1024; }
    else           { tid = bx - 1024; in = W_e1; o = Wt_e; R = 2048; }
    int r0 = (tid >> 4) * 32, c0 = (tid & 15) * 32;
    int a = t >> 3, b4 = t & 7;
    f32x4 v = *(const f32x4*)&in[(size_t)(r0 + a) * 512 + c0 + b4 * 4];
    tile[a][b4 * 4 + 0] = v[0];
    tile[a][b4 * 4 + 1] = v[1];
    tile[a][b4 * 4 + 2] = v[2];
    tile[a][b4 * 4 + 3] = v[3];
    __syncthreads();
    ushort4 o4;
    o4.x = f2bf(tile[b4 * 4 + 0][a]);
    o4.y = f2bf(tile[b4 * 4 + 1][a]);
    o4.z = f2bf(tile[b4 * 4 + 2][a]);
    o4.w = f2bf(tile[b4 * 4 + 3][a]);
    *(ushort4*)&o[(size_t)(c0 + a) * R + r0 + b4 * 4] = o4;
  } else {
    float v = b_s2[0];
    f32x4 o = {v, v, v, v};
    *(f32x4*)&out[t * 4] = o;
  }
}

// ----------------------------------------------------------------- GEMM
// EXACT r8: 256 thr (4 waves, wm = wave*16), tile 64m x 32n, K-step 64,
// grid (16,16,3) = 768 blocks = 3/CU = 12 waves/CU.
__global__ __launch_bounds__(256) void gemm_fused(
    const unsigned short* __restrict__ Aemb,   // [1024][1024] bf16
    const unsigned short* __restrict__ Wt_s,   // [512][1024] bf16
    const unsigned short* __restrict__ Wt_e,   // [512][2048] bf16
    const float* __restrict__ b_s1, const float* __restrict__ w_s2,
    const float* __restrict__ b_e1, float* __restrict__ out,
    float* __restrict__ A_mat, float* __restrict__ C_mat) {
  __shared__ unsigned short Al[64][72];
  __shared__ unsigned short Bl[32][72];
  int z = blockIdx.z;
  int n0 = blockIdx.x * 32;
  int m0 = blockIdx.y * 64;
  const unsigned short* Bmat = (z == 0) ? Wt_s : Wt_e;
  int bstride = (z == 0) ? 1024 : 2048;
  int bofs = (z == 2) ? 1024 : 0;

  int t = threadIdx.x, lane = t & 63, wave = t >> 6;
  int wm = wave * 16;
  int lm = lane & 15, g = lane >> 4;

  f32x4 acc[2];
  acc[0] = (f32x4){0.f, 0.f, 0.f, 0.f};
  acc[1] = (f32x4){0.f, 0.f, 0.f, 0.f};

  int ar = t >> 2, ac = (t & 3) * 16;
  int br = t >> 3, bc = (t & 7) * 8;
  for (int k0 = 0; k0 < 1024; k0 += 64) {
    __syncthreads();
    const unsigned short* ap = &Aemb[(size_t)(m0 + ar) * 1024 + k0 + ac];
    *(uint4*)&Al[ar][ac] = *(const uint4*)ap;
    *(uint4*)&Al[ar][ac + 8] = *(const uint4*)(ap + 8);
    *(uint4*)&Bl[br][bc] =
        *(const uint4*)&Bmat[(size_t)(n0 + br) * bstride + bofs + k0 + bc];
    __syncthreads();
#pragma unroll
    for (int kk = 0; kk < 2; ++kk) {
      bf16x8 af = *(const bf16x8*)&Al[wm + lm][kk * 32 + g * 8];
      bf16x8 b0 = *(const bf16x8*)&Bl[lm][kk * 32 + g * 8];
      bf16x8 b1 = *(const bf16x8*)&Bl[16 + lm][kk * 32 + g * 8];
      acc[0] = __builtin_amdgcn_mfma_f32_16x16x32_bf16(af, b0, acc[0], 0, 0, 0);
      acc[1] = __builtin_amdgcn_mfma_f32_16x16x32_bf16(af, b1, acc[1], 0, 0, 0);
    }
  }

  int col0 = n0 + lm, col1 = n0 + 16 + lm;
  if (z == 0) {
    float bs0 = b_s1[col0], bs1 = b_s1[col1];
    float ws0 = w_s2[col0], ws1 = w_s2[col1];
#pragma unroll
    for (int r = 0; r < 4; ++r) {
      float s = fmaxf(acc[0][r] + bs0, 0.f) * ws0 +
                fmaxf(acc[1][r] + bs1, 0.f) * ws1;
      s += __shfl_xor(s, 1);
      s += __shfl_xor(s, 2);
      s += __shfl_xor(s, 4);
      s += __shfl_xor(s, 8);
      if (lm == 0) atomicAdd(&out[m0 + wm + g * 4 + r], s);
    }
  } else {
    float* Out = (z == 1) ? A_mat : C_mat;
    float b0 = (z == 2) ? b_e1[col0] : 0.f;
    float b1 = (z == 2) ? b_e1[col1] : 0.f;
#pragma unroll
    for (int r = 0; r < 4; ++r) {
      int row = m0 + wm + g * 4 + r;
      Out[(size_t)row * 512 + col0] = acc[0][r] + b0;
      Out[(size_t)row * 512 + col1] = acc[1][r] + b1;
    }
  }
}

// ------------------------------------------------------------- pairwise
// r8 structure with 128-d chunks (4 chunks, 8 barriers instead of 16).
// end[b,i,j] = sum_d relu(A[i,d]+C[j,d])*w[d] + b_e2.
// 512 thr, grid (8,16,2): 32i x 64j tile, 2x2 micro, d-pairs packed f32x2.
__global__ __launch_bounds__(512) void pairwise(
    const float* __restrict__ A_mat, const float* __restrict__ C_mat,
    const float* __restrict__ w_e2, const float* __restrict__ b_e2,
    float* __restrict__ out) {
  __shared__ f32x2 As_p[64][32];   // [dp][i] 16 KB (128-d chunk)
  __shared__ f32x2 Cs_p[64][64];   // [dp][j] 32 KB
  __shared__ f32x2 wl2[256];       //  2 KB
  int t = threadIdx.x;
  int b = blockIdx.z;
  int j0 = blockIdx.x * 64, i0 = blockIdx.y * 32;

  if (t < 256) wl2[t] = *(const f32x2*)&w_e2[2 * t];
  float be2 = b_e2[0];

  int ti = t >> 5, tj = t & 31;
  f32x2 acc2[2][2];
#pragma unroll
  for (int q = 0; q < 2; ++q)
#pragma unroll
    for (int r = 0; r < 2; ++r) acc2[q][r] = (f32x2){0.f, 0.f};

  const float* Ab = A_mat + (size_t)(b * 512 + i0) * 512;
  const float* Cb = C_mat + (size_t)(b * 512 + j0) * 512;
  int si = t & 31, sq = t >> 5;  // A stage: row si, d-quads sq, sq+16
  int sj = t & 63, s2 = t >> 6;  // C stage: row sj, d-quads s2+8p
  f32x2 z2 = {0.f, 0.f};

  for (int ch = 0; ch < 4; ++ch) {
    __syncthreads();
    {
#pragma unroll
      for (int p = 0; p < 2; ++p) {
        int q4 = sq + p * 16;                 // quad index 0..31
        f32x4 va = *(const f32x4*)&Ab[(size_t)si * 512 + ch * 128 + q4 * 4];
        As_p[q4 * 2 + 0][si] = (f32x2){va[0], va[1]};
        As_p[q4 * 2 + 1][si] = (f32x2){va[2], va[3]};
      }
#pragma unroll
      for (int p = 0; p < 4; ++p) {
        int q4 = s2 + p * 8;                  // quad index 0..31
        f32x4 vc = *(const f32x4*)&Cb[(size_t)sj * 512 + ch * 128 + q4 * 4];
        Cs_p[q4 * 2 + 0][sj] = (f32x2){vc[0], vc[1]};
        Cs_p[q4 * 2 + 1][sj] = (f32x2){vc[2], vc[3]};
      }
    }
    __syncthreads();
#pragma unroll 8
    for (int dp = 0; dp < 64; ++dp) {
      f32x2 w2 = wl2[ch * 64 + dp];
      f32x4 av = *(const f32x4*)&As_p[dp][ti * 2];
      f32x4 cv = *(const f32x4*)&Cs_p[dp][tj * 2];
      f32x2 a0 = {av[0], av[1]}, a1 = {av[2], av[3]};
      f32x2 c0 = {cv[0], cv[1]}, c1 = {cv[2], cv[3]};
      acc2[0][0] += __builtin_elementwise_max(a0 + c0, z2) * w2;
      acc2[0][1] += __builtin_elementwise_max(a0 + c1, z2) * w2;
      acc2[1][0] += __builtin_elementwise_max(a1 + c0, z2) * w2;
      acc2[1][1] += __builtin_elementwise_max(a1 + c1, z2) * w2;
    }
  }

  float* oe = out + 1024;
#pragma unroll
  for (int q = 0; q < 2; ++q) {
    int i = i0 + ti * 2 + q;
    float2 vv;
    vv.x = acc2[q][0][0] + acc2[q][0][1] + be2;
    vv.y = acc2[q][1][0] + acc2[q][1][1] + be2;
    *(float2*)&oe[(size_t)(b * 512 + i) * 512 + j0 + tj * 2] = vv;
  }
}

// -------------------------------------------------------------------- launch
extern "C" void kernel_launch(void* const* d_in, const int* in_sizes, int n_in,
                              void* d_out, int out_size, void* d_ws,
                              size_t ws_size, hipStream_t stream) {
  const float* emb  = (const float*)d_in[0];
  const float* W_s1 = (const float*)d_in[1];
  const float* b_s1 = (const float*)d_in[2];
  const float* w_s2 = (const float*)d_in[3];
  const float* b_s2 = (const float*)d_in[4];
  const float* W_e1 = (const float*)d_in[5];
  const float* b_e1 = (const float*)d_in[6];
  const float* w_e2 = (const float*)d_in[7];
  const float* b_e2 = (const float*)d_in[8];
  float* out = (float*)d_out;

  char* ws = (char*)d_ws;
  unsigned short* emb_bf = (unsigned short*)(ws);                  // 2 MB
  unsigned short* Wt_s = (unsigned short*)(ws + 2u * (1u << 20));  // 1 MB
  unsigned short* Wt_e = (unsigned short*)(ws + 3u * (1u << 20));  // 2 MB
  float* A_mat = (float*)(ws + 5u * (1u << 20));                   // 2 MB
  float* C_mat = (float*)(ws + 7u * (1u << 20));                   // 2 MB

  hipLaunchKernelGGL(prep, dim3(2049), dim3(256), 0, stream,
                     emb, W_s1, W_e1, b_s2, emb_bf, Wt_s, Wt_e, out);
  hipLaunchKernelGGL(gemm_fused, dim3(16, 16, 3), dim3(256), 0, stream,
                     emb_bf, Wt_s, Wt_e, b_s1, w_s2, b_e1, out, A_mat, C_mat);
  hipLaunchKernelGGL(pairwise, dim3(8, 16, 2), dim3(512), 0, stream,
                     A_mat, C_mat, w_e2, b_e2, out);
}

// Round 14
// 119.462 us; speedup vs baseline: 1.0554x; 1.0152x over previous
//
#include <hip/hip_runtime.h>
#include <hip/hip_bf16.h>

// FINAL (r8 config, verified best = 118.6us over r5-r13 exploration).
// Harness facts: inputs f32, output f32, threshold 2.5e-2 (bf16 cmp).
// ~85us of dur_us = harness 0xAA poison fills (2x256MiB @ 80% HBM peak).
// Controllable part ~33us: prep ~3, gemm ~6, pairwise ~9, launch/restore rest.
// Exploration ledger (all single-lever, vs r8): 2-wave gemm +9 (latency
// cliff), bf16-C pairwise +4 (VALU-bound, unpack costs > LDS savings),
// 384-blk gemm +7.5 (makespan tail), 128-d chunks +2.7 (barriers not
// binding). Occupancy/balance dominate issue-mix at these grid sizes.
//   1. prep (2049 blocks): emb f32->bf16 | W_s1^T, W_e1^T -> bf16 | out[0:1024]=b_s2
//   2. gemm (16,16,3) x 256 thr: 64m x 32n, wave-tile 16x32, 768 blocks (3/CU)
//      z=0: relu(+b_s1)*w_s2 -> shfl reduce -> atomicAdd out[0:1024]
//      z=1: A_mat f32;  z=2: C_mat = c + b_e1 (f32)
//   3. pairwise (8,16,2) x 512 thr: 32i x 64j, 2x2 micro, packed f32x2 math,
//      64-d chunks, plain contiguous stores.

typedef float f32x4 __attribute__((ext_vector_type(4)));
typedef float f32x2 __attribute__((ext_vector_type(2)));
typedef __bf16 bf16x8 __attribute__((ext_vector_type(8)));

static __device__ __forceinline__ unsigned short f2bf(float f) {
  unsigned int u = __builtin_bit_cast(unsigned int, f);
  u += 0x7FFFu + ((u >> 16) & 1u);  // RNE
  return (unsigned short)(u >> 16);
}

// ----------------------------------------------------------------- prep
__global__ __launch_bounds__(256) void prep(
    const float* __restrict__ emb, const float* __restrict__ W_s1,
    const float* __restrict__ W_e1, const float* __restrict__ b_s2,
    unsigned short* __restrict__ emb_bf, unsigned short* __restrict__ Wt_s,
    unsigned short* __restrict__ Wt_e, float* __restrict__ out) {
  __shared__ float tile[32][33];
  int bx = blockIdx.x, t = threadIdx.x;
  if (bx < 512) {
    int i = bx * 2048 + t * 8;
    f32x4 v0 = *(const f32x4*)&emb[i];
    f32x4 v1 = *(const f32x4*)&emb[i + 4];
    ushort4 o0, o1;
    o0.x = f2bf(v0[0]); o0.y = f2bf(v0[1]);
    o0.z = f2bf(v0[2]); o0.w = f2bf(v0[3]);
    o1.x = f2bf(v1[0]); o1.y = f2bf(v1[1]);
    o1.z = f2bf(v1[2]); o1.w = f2bf(v1[3]);
    *(ushort4*)&emb_bf[i] = o0;
    *(ushort4*)&emb_bf[i + 4] = o1;
  } else if (bx < 2048) {
    const float* in;
    unsigned short* o;
    int R, tid;
    if (bx < 1024) { tid = bx - 512;  in = W_s1; o = Wt_s; R = 1024; }
    else           { tid = bx - 1024; in = W_e1; o = Wt_e; R = 2048; }
    int r0 = (tid >> 4) * 32, c0 = (tid & 15) * 32;
    int a = t >> 3, b4 = t & 7;
    f32x4 v = *(const f32x4*)&in[(size_t)(r0 + a) * 512 + c0 + b4 * 4];
    tile[a][b4 * 4 + 0] = v[0];
    tile[a][b4 * 4 + 1] = v[1];
    tile[a][b4 * 4 + 2] = v[2];
    tile[a][b4 * 4 + 3] = v[3];
    __syncthreads();
    ushort4 o4;
    o4.x = f2bf(tile[b4 * 4 + 0][a]);
    o4.y = f2bf(tile[b4 * 4 + 1][a]);
    o4.z = f2bf(tile[b4 * 4 + 2][a]);
    o4.w = f2bf(tile[b4 * 4 + 3][a]);
    *(ushort4*)&o[(size_t)(c0 + a) * R + r0 + b4 * 4] = o4;
  } else {
    float v = b_s2[0];
    f32x4 o = {v, v, v, v};
    *(f32x4*)&out[t * 4] = o;
  }
}

// ----------------------------------------------------------------- GEMM
// 256 thr (4 waves, wm = wave*16), tile 64m x 32n, K-step 64,
// grid (16,16,3) = 768 blocks = 3/CU = 12 waves/CU.
__global__ __launch_bounds__(256) void gemm_fused(
    const unsigned short* __restrict__ Aemb,   // [1024][1024] bf16
    const unsigned short* __restrict__ Wt_s,   // [512][1024] bf16
    const unsigned short* __restrict__ Wt_e,   // [512][2048] bf16
    const float* __restrict__ b_s1, const float* __restrict__ w_s2,
    const float* __restrict__ b_e1, float* __restrict__ out,
    float* __restrict__ A_mat, float* __restrict__ C_mat) {
  __shared__ unsigned short Al[64][72];
  __shared__ unsigned short Bl[32][72];
  int z = blockIdx.z;
  int n0 = blockIdx.x * 32;
  int m0 = blockIdx.y * 64;
  const unsigned short* Bmat = (z == 0) ? Wt_s : Wt_e;
  int bstride = (z == 0) ? 1024 : 2048;
  int bofs = (z == 2) ? 1024 : 0;

  int t = threadIdx.x, lane = t & 63, wave = t >> 6;
  int wm = wave * 16;
  int lm = lane & 15, g = lane >> 4;

  f32x4 acc[2];
  acc[0] = (f32x4){0.f, 0.f, 0.f, 0.f};
  acc[1] = (f32x4){0.f, 0.f, 0.f, 0.f};

  int ar = t >> 2, ac = (t & 3) * 16;
  int br = t >> 3, bc = (t & 7) * 8;
  for (int k0 = 0; k0 < 1024; k0 += 64) {
    __syncthreads();
    const unsigned short* ap = &Aemb[(size_t)(m0 + ar) * 1024 + k0 + ac];
    *(uint4*)&Al[ar][ac] = *(const uint4*)ap;
    *(uint4*)&Al[ar][ac + 8] = *(const uint4*)(ap + 8);
    *(uint4*)&Bl[br][bc] =
        *(const uint4*)&Bmat[(size_t)(n0 + br) * bstride + bofs + k0 + bc];
    __syncthreads();
#pragma unroll
    for (int kk = 0; kk < 2; ++kk) {
      bf16x8 af = *(const bf16x8*)&Al[wm + lm][kk * 32 + g * 8];
      bf16x8 b0 = *(const bf16x8*)&Bl[lm][kk * 32 + g * 8];
      bf16x8 b1 = *(const bf16x8*)&Bl[16 + lm][kk * 32 + g * 8];
      acc[0] = __builtin_amdgcn_mfma_f32_16x16x32_bf16(af, b0, acc[0], 0, 0, 0);
      acc[1] = __builtin_amdgcn_mfma_f32_16x16x32_bf16(af, b1, acc[1], 0, 0, 0);
    }
  }

  int col0 = n0 + lm, col1 = n0 + 16 + lm;
  if (z == 0) {
    float bs0 = b_s1[col0], bs1 = b_s1[col1];
    float ws0 = w_s2[col0], ws1 = w_s2[col1];
#pragma unroll
    for (int r = 0; r < 4; ++r) {
      float s = fmaxf(acc[0][r] + bs0, 0.f) * ws0 +
                fmaxf(acc[1][r] + bs1, 0.f) * ws1;
      s += __shfl_xor(s, 1);
      s += __shfl_xor(s, 2);
      s += __shfl_xor(s, 4);
      s += __shfl_xor(s, 8);
      if (lm == 0) atomicAdd(&out[m0 + wm + g * 4 + r], s);
    }
  } else {
    float* Out = (z == 1) ? A_mat : C_mat;
    float b0 = (z == 2) ? b_e1[col0] : 0.f;
    float b1 = (z == 2) ? b_e1[col1] : 0.f;
#pragma unroll
    for (int r = 0; r < 4; ++r) {
      int row = m0 + wm + g * 4 + r;
      Out[(size_t)row * 512 + col0] = acc[0][r] + b0;
      Out[(size_t)row * 512 + col1] = acc[1][r] + b1;
    }
  }
}

// ------------------------------------------------------------- pairwise
// end[b,i,j] = sum_d relu(A[i,d]+C[j,d])*w[d] + b_e2, 64-d chunks.
// 512 thr, grid (8,16,2): 32i x 64j tile, 2x2 micro, d-pairs packed f32x2.
__global__ __launch_bounds__(512) void pairwise(
    const float* __restrict__ A_mat, const float* __restrict__ C_mat,
    const float* __restrict__ w_e2, const float* __restrict__ b_e2,
    float* __restrict__ out) {
  __shared__ f32x2 As_p[32][32];   // [dp][i]   8 KB (per 64-d chunk)
  __shared__ f32x2 Cs_p[32][64];   // [dp][j]  16 KB
  __shared__ f32x2 wl2[256];
  int t = threadIdx.x;
  int b = blockIdx.z;
  int j0 = blockIdx.x * 64, i0 = blockIdx.y * 32;

  if (t < 256) wl2[t] = *(const f32x2*)&w_e2[2 * t];
  float be2 = b_e2[0];

  int ti = t >> 5, tj = t & 31;
  f32x2 acc2[2][2];
#pragma unroll
  for (int q = 0; q < 2; ++q)
#pragma unroll
    for (int r = 0; r < 2; ++r) acc2[q][r] = (f32x2){0.f, 0.f};

  const float* Ab = A_mat + (size_t)(b * 512 + i0) * 512;
  const float* Cb = C_mat + (size_t)(b * 512 + j0) * 512;
  int si = t & 31, sq = t >> 5;  // A stage: row si, d-quad sq (0..15)
  int sj = t & 63, s2 = t >> 6;  // C stage: row sj, d-oct  s2 (0..7)
  f32x2 z2 = {0.f, 0.f};

  for (int ch = 0; ch < 8; ++ch) {
    __syncthreads();
    {
      f32x4 va = *(const f32x4*)&Ab[(size_t)si * 512 + ch * 64 + sq * 4];
      As_p[sq * 2 + 0][si] = (f32x2){va[0], va[1]};
      As_p[sq * 2 + 1][si] = (f32x2){va[2], va[3]};
      f32x4 v0 = *(const f32x4*)&Cb[(size_t)sj * 512 + ch * 64 + s2 * 8];
      f32x4 v1 = *(const f32x4*)&Cb[(size_t)sj * 512 + ch * 64 + s2 * 8 + 4];
      Cs_p[s2 * 4 + 0][sj] = (f32x2){v0[0], v0[1]};
      Cs_p[s2 * 4 + 1][sj] = (f32x2){v0[2], v0[3]};
      Cs_p[s2 * 4 + 2][sj] = (f32x2){v1[0], v1[1]};
      Cs_p[s2 * 4 + 3][sj] = (f32x2){v1[2], v1[3]};
    }
    __syncthreads();
#pragma unroll 8
    for (int dp = 0; dp < 32; ++dp) {
      f32x2 w2 = wl2[ch * 32 + dp];
      f32x4 av = *(const f32x4*)&As_p[dp][ti * 2];
      f32x4 cv = *(const f32x4*)&Cs_p[dp][tj * 2];
      f32x2 a0 = {av[0], av[1]}, a1 = {av[2], av[3]};
      f32x2 c0 = {cv[0], cv[1]}, c1 = {cv[2], cv[3]};
      acc2[0][0] += __builtin_elementwise_max(a0 + c0, z2) * w2;
      acc2[0][1] += __builtin_elementwise_max(a0 + c1, z2) * w2;
      acc2[1][0] += __builtin_elementwise_max(a1 + c0, z2) * w2;
      acc2[1][1] += __builtin_elementwise_max(a1 + c1, z2) * w2;
    }
  }

  float* oe = out + 1024;
#pragma unroll
  for (int q = 0; q < 2; ++q) {
    int i = i0 + ti * 2 + q;
    float2 vv;
    vv.x = acc2[q][0][0] + acc2[q][0][1] + be2;
    vv.y = acc2[q][1][0] + acc2[q][1][1] + be2;
    *(float2*)&oe[(size_t)(b * 512 + i) * 512 + j0 + tj * 2] = vv;
  }
}

// -------------------------------------------------------------------- launch
extern "C" void kernel_launch(void* const* d_in, const int* in_sizes, int n_in,
                              void* d_out, int out_size, void* d_ws,
                              size_t ws_size, hipStream_t stream) {
  const float* emb  = (const float*)d_in[0];
  const float* W_s1 = (const float*)d_in[1];
  const float* b_s1 = (const float*)d_in[2];
  const float* w_s2 = (const float*)d_in[3];
  const float* b_s2 = (const float*)d_in[4];
  const float* W_e1 = (const float*)d_in[5];
  const float* b_e1 = (const float*)d_in[6];
  const float* w_e2 = (const float*)d_in[7];
  const float* b_e2 = (const float*)d_in[8];
  float* out = (float*)d_out;

  char* ws = (char*)d_ws;
  unsigned short* emb_bf = (unsigned short*)(ws);                  // 2 MB
  unsigned short* Wt_s = (unsigned short*)(ws + 2u * (1u << 20));  // 1 MB
  unsigned short* Wt_e = (unsigned short*)(ws + 3u * (1u << 20));  // 2 MB
  float* A_mat = (float*)(ws + 5u * (1u << 20));                   // 2 MB
  float* C_mat = (float*)(ws + 7u * (1u << 20));                   // 2 MB

  hipLaunchKernelGGL(prep, dim3(2049), dim3(256), 0, stream,
                     emb, W_s1, W_e1, b_s2, emb_bf, Wt_s, Wt_e, out);
  hipLaunchKernelGGL(gemm_fused, dim3(16, 16, 3), dim3(256), 0, stream,
                     emb_bf, Wt_s, Wt_e, b_s1, w_s2, b_e1, out, A_mat, C_mat);
  hipLaunchKernelGGL(pairwise, dim3(8, 16, 2), dim3(512), 0, stream,
                     A_mat, C_mat, w_e2, b_e2, out);
}